// Round 1
// baseline (242.322 us; speedup 1.0000x reference)
//
#include <hip/hip_runtime.h>

// Problem constants (fixed by the reference)
#define NN 512
#define KK 17
#define WW 48
#define HH 64
#define HW (WW * HH)        // 3072 pixels per (n,k)
#define NK (NN * KK)        // 8704 blocks

// Loss = mean over [N,K,H,W] of (tw * (g*mask - teacher))^2
// g(n,k,h,w) = exp(-0.5*((w-mu_x)^2/(sx^2+eps))) * exp(-0.5*((h-mu_y)^2/(sy^2+eps)))
// Separable: stage exp_x[48] and exp_y[64] in LDS per block; HBM-bound on teacher.

__global__ __launch_bounds__(256) void reg2hm_loss_kernel(
    const float* __restrict__ pred,      // [N,K,2]
    const float* __restrict__ sigma,     // [N,K,2]
    const float* __restrict__ teacher,   // [N,K,H,W]
    const float* __restrict__ twgt,      // [N,K,1]
    float* __restrict__ out)             // [1]
{
    __shared__ float ex[WW];
    __shared__ float ey[HH];
    __shared__ float wave_sums[4];

    const int nk = blockIdx.x;
    const int t  = threadIdx.x;

    // Per-block (wave-uniform) scalars — broadcast loads
    const float mu_x = pred[nk * 2 + 0] * (float)WW;
    const float mu_y = pred[nk * 2 + 1] * (float)HH;
    const float sx   = sigma[nk * 2 + 0];
    const float sy   = sigma[nk * 2 + 1];

    const bool m = (mu_x - 3.0f * sx < (float)WW) &&
                   (mu_y - 3.0f * sy < (float)HH) &&
                   (mu_x + 3.0f * sx + 1.0f >= 0.0f) &&
                   (mu_y + 3.0f * sy + 1.0f >= 0.0f);
    const float mask = m ? 1.0f : 0.0f;
    const float wgt  = twgt[nk] * mask;   // ==0 kills both target and weight terms

    const float inv2sx = 0.5f / (sx * sx + 1e-9f);
    const float inv2sy = 0.5f / (sy * sy + 1e-9f);

    // Stage separable gaussians: threads 0..47 -> ex, 48..111 -> ey
    if (t < WW) {
        float d = (float)t - mu_x;
        ex[t] = __expf(-d * d * inv2sx);
    } else if (t < WW + HH) {
        float d = (float)(t - WW) - mu_y;
        ey[t - WW] = __expf(-d * d * inv2sy);
    }
    __syncthreads();

    // 3072 floats = 768 float4; 256 threads x 3 iterations.
    // W=48 divisible by 4 => each float4 stays within one row (constant h).
    const float4* tp = (const float4*)(teacher + (size_t)nk * HW);
    float sum = 0.0f;
#pragma unroll
    for (int j = 0; j < 3; ++j) {
        const int i = t + j * 256;     // [0, 768)
        const int p = i * 4;           // pixel index
        const int h = p / WW;
        const int w = p - h * WW;
        const float4 tv = tp[i];
        const float eyh = ey[h];
        float v0 = wgt * (ex[w + 0] * eyh - tv.x);
        float v1 = wgt * (ex[w + 1] * eyh - tv.y);
        float v2 = wgt * (ex[w + 2] * eyh - tv.z);
        float v3 = wgt * (ex[w + 3] * eyh - tv.w);
        sum += v0 * v0 + v1 * v1 + v2 * v2 + v3 * v3;
    }

    // Wave(64)-wide shuffle reduction
#pragma unroll
    for (int off = 32; off > 0; off >>= 1)
        sum += __shfl_down(sum, off, 64);

    const int wave = t >> 6;
    const int lane = t & 63;
    if (lane == 0) wave_sums[wave] = sum;
    __syncthreads();

    if (t == 0) {
        float s = wave_sums[0] + wave_sums[1] + wave_sums[2] + wave_sums[3];
        atomicAdd(out, s * (1.0f / ((float)NN * KK * HW)));
    }
}

extern "C" void kernel_launch(void* const* d_in, const int* in_sizes, int n_in,
                              void* d_out, int out_size, void* d_ws, size_t ws_size,
                              hipStream_t stream) {
    const float* pred    = (const float*)d_in[0];
    const float* sigma   = (const float*)d_in[1];
    const float* teacher = (const float*)d_in[2];
    const float* twgt    = (const float*)d_in[3];
    float* out = (float*)d_out;

    // d_out is re-poisoned to 0xAA before every timed launch — zero it first.
    hipMemsetAsync(out, 0, sizeof(float), stream);
    reg2hm_loss_kernel<<<NK, 256, 0, stream>>>(pred, sigma, teacher, twgt, out);
}

// Round 2
// 167.316 us; speedup vs baseline: 1.4483x; 1.4483x over previous
//
#include <hip/hip_runtime.h>

// Problem constants (fixed by the reference)
#define NN 512
#define KK 17
#define WW 48
#define HH 64
#define HW (WW * HH)          // 3072 pixels per (n,k)
#define NK (NN * KK)          // 8704 items
#define ITEMS_PER_BLOCK 4
#define NBLK (NK / ITEMS_PER_BLOCK)   // 2176 blocks, exact

// Loss = mean over [N,K,H,W] of (tw*mask * (g - teacher))^2, g separable.
// Stage 1: each block handles 4 (n,k) items, writes ONE raw partial sum to ws.
// Stage 2: one block reduces the 2176 partials -> out[0]. No global atomics.

__global__ __launch_bounds__(256) void reg2hm_partial_kernel(
    const float* __restrict__ pred,      // [N,K,2]
    const float* __restrict__ sigma,     // [N,K,2]
    const float* __restrict__ teacher,   // [N,K,H,W]
    const float* __restrict__ twgt,      // [N,K,1]
    float* __restrict__ ws)              // [NBLK] partial sums
{
    __shared__ float ex4[ITEMS_PER_BLOCK * WW];   // 192
    __shared__ float ey4[ITEMS_PER_BLOCK * HH];   // 256
    __shared__ float sw[ITEMS_PER_BLOCK];
    __shared__ float wave_sums[4];

    const int b   = blockIdx.x;
    const int nk0 = b * ITEMS_PER_BLOCK;
    const int t   = threadIdx.x;

    // Per-item weight (mask * target_weight)
    if (t < ITEMS_PER_BLOCK) {
        const int nk = nk0 + t;
        const float mu_x = pred[nk * 2 + 0] * (float)WW;
        const float mu_y = pred[nk * 2 + 1] * (float)HH;
        const float sx   = sigma[nk * 2 + 0];
        const float sy   = sigma[nk * 2 + 1];
        const bool m = (mu_x - 3.0f * sx < (float)WW) &&
                       (mu_y - 3.0f * sy < (float)HH) &&
                       (mu_x + 3.0f * sx + 1.0f >= 0.0f) &&
                       (mu_y + 3.0f * sy + 1.0f >= 0.0f);
        sw[t] = twgt[nk] * (m ? 1.0f : 0.0f);
    }

    // Stage separable exponentials for all 4 items: 4*(48+64)=448 entries.
    for (int i = t; i < ITEMS_PER_BLOCK * (WW + HH); i += 256) {
        const int item = i / (WW + HH);
        const int r    = i - item * (WW + HH);
        const int nk   = nk0 + item;
        if (r < WW) {
            const float mu = pred[nk * 2 + 0] * (float)WW;
            const float s  = sigma[nk * 2 + 0];
            const float d  = (float)r - mu;
            ex4[item * WW + r] = __expf(-d * d * (0.5f / (s * s + 1e-9f)));
        } else {
            const float mu = pred[nk * 2 + 1] * (float)HH;
            const float s  = sigma[nk * 2 + 1];
            const float d  = (float)(r - WW) - mu;
            ey4[item * HH + (r - WW)] = __expf(-d * d * (0.5f / (s * s + 1e-9f)));
        }
    }
    __syncthreads();

    // 4 items x 768 float4 each; 12 independent float4 loads per thread.
    float sum = 0.0f;
#pragma unroll
    for (int item = 0; item < ITEMS_PER_BLOCK; ++item) {
        const float4* tp = (const float4*)(teacher + (size_t)(nk0 + item) * HW);
        const float wgt = sw[item];
        const float* exb = &ex4[item * WW];
        const float* eyb = &ey4[item * HH];
#pragma unroll
        for (int j = 0; j < 3; ++j) {
            const int i = t + j * 256;     // [0, 768)
            const int p = i * 4;           // pixel index
            const int h = p / WW;
            const int w = p - h * WW;
            const float4 tv = tp[i];
            const float eyh = eyb[h];
            const float v0 = wgt * (exb[w + 0] * eyh - tv.x);
            const float v1 = wgt * (exb[w + 1] * eyh - tv.y);
            const float v2 = wgt * (exb[w + 2] * eyh - tv.z);
            const float v3 = wgt * (exb[w + 3] * eyh - tv.w);
            sum += v0 * v0 + v1 * v1 + v2 * v2 + v3 * v3;
        }
    }

    // Wave(64) shuffle reduction, then cross-wave via LDS.
#pragma unroll
    for (int off = 32; off > 0; off >>= 1)
        sum += __shfl_down(sum, off, 64);

    const int wave = t >> 6;
    const int lane = t & 63;
    if (lane == 0) wave_sums[wave] = sum;
    __syncthreads();

    if (t == 0)
        ws[b] = wave_sums[0] + wave_sums[1] + wave_sums[2] + wave_sums[3];
}

__global__ __launch_bounds__(256) void reg2hm_final_kernel(
    const float* __restrict__ ws, float* __restrict__ out)
{
    __shared__ float wave_sums[4];
    const int t = threadIdx.x;
    float sum = 0.0f;
    for (int i = t; i < NBLK; i += 256) sum += ws[i];
#pragma unroll
    for (int off = 32; off > 0; off >>= 1)
        sum += __shfl_down(sum, off, 64);
    const int wave = t >> 6;
    const int lane = t & 63;
    if (lane == 0) wave_sums[wave] = sum;
    __syncthreads();
    if (t == 0) {
        const float total = wave_sums[0] + wave_sums[1] + wave_sums[2] + wave_sums[3];
        out[0] = total * (1.0f / ((float)NN * KK * HW));
    }
}

extern "C" void kernel_launch(void* const* d_in, const int* in_sizes, int n_in,
                              void* d_out, int out_size, void* d_ws, size_t ws_size,
                              hipStream_t stream) {
    const float* pred    = (const float*)d_in[0];
    const float* sigma   = (const float*)d_in[1];
    const float* teacher = (const float*)d_in[2];
    const float* twgt    = (const float*)d_in[3];
    float* out = (float*)d_out;
    float* ws  = (float*)d_ws;   // needs NBLK*4 = 8704 bytes

    reg2hm_partial_kernel<<<NBLK, 256, 0, stream>>>(pred, sigma, teacher, twgt, ws);
    reg2hm_final_kernel<<<1, 256, 0, stream>>>(ws, out);
}

// Round 3
// 166.006 us; speedup vs baseline: 1.4597x; 1.0079x over previous
//
#include <hip/hip_runtime.h>

// Problem constants (fixed by the reference)
#define NN 512
#define KK 17
#define WW 48
#define HH 64
#define HW (WW * HH)          // 3072 pixels per (n,k)
#define NK (NN * KK)          // 8704 items
#define IPB 4                 // items per block
#define NBLK (NK / IPB)       // 2176 blocks, exact

// Loss = mean over [N,K,H,W] of (tw*mask * (g - teacher))^2, g separable:
// g = ex[w]*ey[h]. Stage ex (as float4) + ey in LDS per block.
// Stage 1: each block handles 4 (n,k) items; ALL 12 teacher float4 loads are
// issued into registers first (guaranteed MLP), then squared-diff reduce.
// One raw partial per block -> ws. Stage 2: tiny reduce -> out[0]. No atomics.

__global__ __launch_bounds__(256, 4) void reg2hm_partial_kernel(
    const float* __restrict__ pred,      // [N,K,2]
    const float* __restrict__ sigma,     // [N,K,2]
    const float* __restrict__ teacher,   // [N,K,H,W]
    const float* __restrict__ twgt,      // [N,K,1]
    float* __restrict__ ws)              // [NBLK] partial sums
{
    __shared__ float4 ex4[IPB][WW / 4];   // 12 float4 per item
    __shared__ float  ey4[IPB][HH];       // 64 per item
    __shared__ float  sw[IPB];
    __shared__ float  wave_sums[4];

    const int b   = blockIdx.x;
    const int nk0 = b * IPB;
    const int t   = threadIdx.x;

    // Per-item weight (mask * target_weight)
    if (t < IPB) {
        const int nk = nk0 + t;
        const float mu_x = pred[nk * 2 + 0] * (float)WW;
        const float mu_y = pred[nk * 2 + 1] * (float)HH;
        const float sx   = sigma[nk * 2 + 0];
        const float sy   = sigma[nk * 2 + 1];
        const bool m = (mu_x - 3.0f * sx < (float)WW) &&
                       (mu_y - 3.0f * sy < (float)HH) &&
                       (mu_x + 3.0f * sx + 1.0f >= 0.0f) &&
                       (mu_y + 3.0f * sy + 1.0f >= 0.0f);
        sw[t] = twgt[nk] * (m ? 1.0f : 0.0f);
    }

    // Stage separable exponentials: 4*(48+64) = 448 entries, 2 passes.
    float* exf = (float*)ex4;
    for (int i = t; i < IPB * (WW + HH); i += 256) {
        const int item = i / (WW + HH);
        const int r    = i - item * (WW + HH);
        const int nk   = nk0 + item;
        if (r < WW) {
            const float mu = pred[nk * 2 + 0] * (float)WW;
            const float s  = sigma[nk * 2 + 0];
            const float d  = (float)r - mu;
            exf[item * WW + r] = __expf(-d * d * (0.5f / (s * s + 1e-9f)));
        } else {
            const float mu = pred[nk * 2 + 1] * (float)HH;
            const float s  = sigma[nk * 2 + 1];
            const float d  = (float)(r - WW) - mu;
            ey4[item][r - WW] = __expf(-d * d * (0.5f / (s * s + 1e-9f)));
        }
    }
    __syncthreads();

    // ---- Load phase: issue all 12 float4 loads before any use (MLP) ----
    float4 tv[IPB * 3];
#pragma unroll
    for (int item = 0; item < IPB; ++item) {
        const float4* tp = (const float4*)(teacher + (size_t)(nk0 + item) * HW);
#pragma unroll
        for (int j = 0; j < 3; ++j)
            tv[item * 3 + j] = tp[t + j * 256];
    }

    // ---- Compute phase ----
    // float4 index i in [0,768): pixel p = 4i, h = i/12, x-segment s = i%12.
    float total = 0.0f;
#pragma unroll
    for (int item = 0; item < IPB; ++item) {
        float acc = 0.0f;
#pragma unroll
        for (int j = 0; j < 3; ++j) {
            const int i = t + j * 256;
            const int h = i / 12;
            const int s = i - h * 12;
            const float4 e  = ex4[item][s];
            const float  ey = ey4[item][h];
            const float4 v  = tv[item * 3 + j];
            const float d0 = e.x * ey - v.x;
            const float d1 = e.y * ey - v.y;
            const float d2 = e.z * ey - v.z;
            const float d3 = e.w * ey - v.w;
            acc += d0 * d0 + d1 * d1 + d2 * d2 + d3 * d3;
        }
        total += sw[item] * sw[item] * acc;
    }

    // Wave(64) shuffle reduction, then cross-wave via LDS.
#pragma unroll
    for (int off = 32; off > 0; off >>= 1)
        total += __shfl_down(total, off, 64);

    const int wave = t >> 6;
    const int lane = t & 63;
    if (lane == 0) wave_sums[wave] = total;
    __syncthreads();

    if (t == 0)
        ws[b] = wave_sums[0] + wave_sums[1] + wave_sums[2] + wave_sums[3];
}

__global__ __launch_bounds__(256) void reg2hm_final_kernel(
    const float* __restrict__ ws, float* __restrict__ out)
{
    __shared__ float wave_sums[4];
    const int t = threadIdx.x;
    float sum = 0.0f;
    for (int i = t; i < NBLK; i += 256) sum += ws[i];
#pragma unroll
    for (int off = 32; off > 0; off >>= 1)
        sum += __shfl_down(sum, off, 64);
    const int wave = t >> 6;
    const int lane = t & 63;
    if (lane == 0) wave_sums[wave] = sum;
    __syncthreads();
    if (t == 0) {
        const float total = wave_sums[0] + wave_sums[1] + wave_sums[2] + wave_sums[3];
        out[0] = total * (1.0f / ((float)NN * KK * HW));
    }
}

extern "C" void kernel_launch(void* const* d_in, const int* in_sizes, int n_in,
                              void* d_out, int out_size, void* d_ws, size_t ws_size,
                              hipStream_t stream) {
    const float* pred    = (const float*)d_in[0];
    const float* sigma   = (const float*)d_in[1];
    const float* teacher = (const float*)d_in[2];
    const float* twgt    = (const float*)d_in[3];
    float* out = (float*)d_out;
    float* ws  = (float*)d_ws;   // needs NBLK*4 = 8704 bytes

    reg2hm_partial_kernel<<<NBLK, 256, 0, stream>>>(pred, sigma, teacher, twgt, ws);
    reg2hm_final_kernel<<<1, 256, 0, stream>>>(ws, out);
}